// Round 5
// baseline (296.753 us; speedup 1.0000x reference)
//
#include <hip/hip_runtime.h>
#include <hip/hip_bf16.h>
#include <math.h>

// Problem constants (CrossAttention_14955076125227)
//   B=4, N=2048, M=2048, Dq=512, Dc=768, H=8, Dh=64, inner=512
#define BB 4
#define NN 2048
#define MM 2048
#define DQ 512
#define DC 768
#define NH 8
#define DH 64
#define INNER 512
#define KVS 1024   // fused K|V row stride (bf16 elems)

typedef short bf16x8 __attribute__((ext_vector_type(8)));
typedef float f32x4  __attribute__((ext_vector_type(4)));

__device__ inline short fbf(float f) {
    __hip_bfloat16 h = __float2bfloat16(f);
    return __builtin_bit_cast(short, h);
}

// async global->LDS, 16 B per lane. LDS dest is wave-uniform base; HW adds lane*16.
__device__ inline void gld16(const void* gptr, void* lds_uniform_base) {
    __builtin_amdgcn_global_load_lds(
        (const __attribute__((address_space(1))) void*)gptr,
        (__attribute__((address_space(3))) void*)lds_uniform_base, 16, 0, 0);
}

// ---------------------------------------------------------------------------
// LayerNorm -> bf16 out (feeds MFMA GEMMs). One block per row.
// ---------------------------------------------------------------------------
__global__ __launch_bounds__(256) void layernorm_bf16(
    const float* __restrict__ in, const float* __restrict__ g,
    const float* __restrict__ b, short* __restrict__ out, int D)
{
    const int row = blockIdx.x;
    const float* x = in + (size_t)row * D;
    float s = 0.f, s2 = 0.f;
    for (int d = threadIdx.x; d < D; d += 256) {
        float v = x[d];
        s += v; s2 += v * v;
    }
    __shared__ float red[2][4];
    #pragma unroll
    for (int off = 32; off; off >>= 1) {
        s  += __shfl_down(s,  off, 64);
        s2 += __shfl_down(s2, off, 64);
    }
    const int wave = threadIdx.x >> 6, lane = threadIdx.x & 63;
    if (lane == 0) { red[0][wave] = s; red[1][wave] = s2; }
    __syncthreads();
    if (threadIdx.x == 0) {
        float ts = red[0][0] + red[0][1] + red[0][2] + red[0][3];
        float t2 = red[1][0] + red[1][1] + red[1][2] + red[1][3];
        float mu = ts / (float)D;
        float var = t2 / (float)D - mu * mu;
        red[0][0] = mu;
        red[1][0] = rsqrtf(var + 1e-5f);
    }
    __syncthreads();
    const float mu = red[0][0], rstd = red[1][0];
    short* o = out + (size_t)row * D;
    for (int d = threadIdx.x; d < D; d += 256)
        o[d] = fbf((x[d] - mu) * rstd * g[d] + b[d]);
}

// ---------------------------------------------------------------------------
// Final LayerNorm with fused residual: out = LN(bf16(ob) + x) (fp32 out)
// Specialized D=512: 2 elements/thread held in registers.
// ---------------------------------------------------------------------------
__global__ __launch_bounds__(256) void layernorm_res_f32(
    const short* __restrict__ ob, const float* __restrict__ x,
    const float* __restrict__ g, const float* __restrict__ b,
    float* __restrict__ out)
{
    const int row = blockIdx.x;
    const int t = threadIdx.x;
    const size_t base = (size_t)row * DQ;
    float v0, v1;
    {
        unsigned u0 = (unsigned)(unsigned short)ob[base + t];
        unsigned u1 = (unsigned)(unsigned short)ob[base + t + 256];
        v0 = __builtin_bit_cast(float, u0 << 16) + x[base + t];
        v1 = __builtin_bit_cast(float, u1 << 16) + x[base + t + 256];
    }
    float s = v0 + v1, s2 = v0 * v0 + v1 * v1;
    __shared__ float red[2][4];
    #pragma unroll
    for (int off = 32; off; off >>= 1) {
        s  += __shfl_down(s,  off, 64);
        s2 += __shfl_down(s2, off, 64);
    }
    const int wave = t >> 6, lane = t & 63;
    if (lane == 0) { red[0][wave] = s; red[1][wave] = s2; }
    __syncthreads();
    if (t == 0) {
        float ts = red[0][0] + red[0][1] + red[0][2] + red[0][3];
        float t2 = red[1][0] + red[1][1] + red[1][2] + red[1][3];
        float mu = ts / (float)DQ;
        float var = t2 / (float)DQ - mu * mu;
        red[0][0] = mu;
        red[1][0] = rsqrtf(var + 1e-5f);
    }
    __syncthreads();
    const float mu = red[0][0], rstd = red[1][0];
    out[base + t]       = (v0 - mu) * rstd * g[t]       + b[t];
    out[base + t + 256] = (v1 - mu) * rstd * g[t + 256] + b[t + 256];
}

// ---------------------------------------------------------------------------
// Transpose + fp32->bf16 weight conversion: W[K][512] -> Wt[512][K]
// ---------------------------------------------------------------------------
__global__ __launch_bounds__(256) void transpose_cvt(
    const float* __restrict__ W, short* __restrict__ Wt, int K)
{
    __shared__ float tile[32][33];
    const int t = threadIdx.x;
    const int n0 = blockIdx.x * 32, k0 = blockIdx.y * 32;
    const int r = t >> 3, c4 = (t & 7) * 4;
    float4 vv = *(const float4*)&W[(size_t)(k0 + r) * 512 + n0 + c4];
    tile[c4 + 0][r] = vv.x; tile[c4 + 1][r] = vv.y;
    tile[c4 + 2][r] = vv.z; tile[c4 + 3][r] = vv.w;
    __syncthreads();
    short4 s;
    s.x = fbf(tile[r][c4 + 0]); s.y = fbf(tile[r][c4 + 1]);
    s.z = fbf(tile[r][c4 + 2]); s.w = fbf(tile[r][c4 + 3]);
    *(short4*)&Wt[(size_t)(n0 + r) * K + k0 + c4] = s;
}

// ---------------------------------------------------------------------------
// m97-pattern bf16 MFMA GEMM: C[R x Nout] = A[R x K] @ Wt[Nout x K]^T
// Tile 128 x (32*TNT), BK=32, 256 thr (4 waves 2x2; wave = 64 x 16*TNT).
// ---------------------------------------------------------------------------
#define GBM 128
#define GBK 32

template <int TNT>
__global__ __launch_bounds__(256) void gemm_mfma(
    const short* __restrict__ A, const short* __restrict__ Bt,
    int K, int Nout, float oscale,
    short* __restrict__ outb, float* __restrict__ outf,
    const float* __restrict__ bias, const float* __restrict__ resid)
{
    constexpr int GBN = 32 * TNT;
    __shared__ short As[GBM * GBK];
    __shared__ short Bs[GBN * GBK];
    const int t = threadIdx.x;
    const int w = t >> 6, lane = t & 63;
    const int quad = lane >> 4, l16 = lane & 15;
    const int m0 = blockIdx.y * GBM, n0 = blockIdx.x * GBN;
    const int wm = (w >> 1) * 64, wn = (w & 1) * (16 * TNT);

    f32x4 acc[4][TNT];
    #pragma unroll
    for (int i = 0; i < 4; ++i)
        #pragma unroll
        for (int j = 0; j < TNT; ++j) acc[i][j] = (f32x4){0.f, 0.f, 0.f, 0.f};

    for (int kt = 0; kt < K; kt += GBK) {
        __syncthreads();
        #pragma unroll
        for (int i = 0; i < 2; ++i) {   // A: 128 rows x 32k = 512 chunks
            const int j = w * 2 + i;
            const int c = j * 64 + lane;
            gld16(&A[(size_t)(m0 + (c >> 2)) * K + kt + (c & 3) * 8],
                  (char*)As + j * 1024);
        }
        #pragma unroll
        for (int i = 0; i < TNT / 2; ++i) {  // B: GBN rows x 32k
            const int j = w * (TNT / 2) + i;
            const int c = j * 64 + lane;
            gld16(&Bt[(size_t)(n0 + (c >> 2)) * K + kt + (c & 3) * 8],
                  (char*)Bs + j * 1024);
        }
        __syncthreads();

        bf16x8 af[4], bfr[TNT];
        #pragma unroll
        for (int mt = 0; mt < 4; ++mt)
            af[mt] = *(bf16x8*)&As[(wm + mt * 16 + l16) * GBK + quad * 8];
        #pragma unroll
        for (int nt = 0; nt < TNT; ++nt)
            bfr[nt] = *(bf16x8*)&Bs[(wn + nt * 16 + l16) * GBK + quad * 8];
        #pragma unroll
        for (int mt = 0; mt < 4; ++mt)
            #pragma unroll
            for (int nt = 0; nt < TNT; ++nt)
                acc[mt][nt] = __builtin_amdgcn_mfma_f32_16x16x32_bf16(
                    af[mt], bfr[nt], acc[mt][nt], 0, 0, 0);
    }

    #pragma unroll
    for (int mt = 0; mt < 4; ++mt) {
        #pragma unroll
        for (int r = 0; r < 4; ++r) {
            const int m = m0 + wm + mt * 16 + quad * 4 + r;
            #pragma unroll
            for (int nt = 0; nt < TNT; ++nt) {
                const int n = n0 + wn + nt * 16 + l16;
                float v = acc[mt][nt][r] * oscale;
                if (bias)  v += bias[n];
                if (resid) v += resid[(size_t)m * Nout + n];
                if (outb) outb[(size_t)m * Nout + n] = fbf(v);
                else      outf[(size_t)m * Nout + n] = v;
            }
        }
    }
}

// ---------------------------------------------------------------------------
// bf16-MFMA flash attention v3: S^T form, no-max softmax, 2 i-tiles/wave.
// q is PRE-SCALED by 0.125*log2(e) in the q-proj GEMM (p = exp2(s)).
// Block = 4 waves x 32 Q rows = 128 rows; grid (N/128, H, B).
// Every K/V fragment read feeds 2 MFMAs (one per i-tile) -> LDS bytes/FLOP
// halved vs the 1-i-tile version (which was LDS-BW bound at ~4 GB total).
// ---------------------------------------------------------------------------
#define QT 128
#define JT 64
#define KSTR 72   // 144 B rows: 16B-aligned, 2-way bank alias max (free)
#define PSTR 72

__global__ __launch_bounds__(256) void attention_mfma(
    const short* __restrict__ q, const short* __restrict__ kv,
    short* __restrict__ o)
{
    const int b = blockIdx.z, h = blockIdx.y;
    const int i0 = blockIdx.x * QT;
    const int t = threadIdx.x;
    const int wave = t >> 6, lane = t & 63;
    const int quad = lane >> 4, l16 = lane & 15;

    __shared__ short Ks[JT][KSTR];       // K[j][d]
    __shared__ short Vt[80][KSTR];       // 0..63: V^T[d][j]; 64: ones; 65..79: 0
    __shared__ short Ps[4][32][PSTR];    // per-wave P[i][j], 2 i-tiles

    // init ones/zero rows once (staging only touches rows 0..63)
    for (int idx = t; idx < 16 * KSTR; idx += 256) {
        const int rr = idx / KSTR;
        Vt[64 + rr][idx % KSTR] = (rr == 0) ? (short)0x3F80 : (short)0;  // bf16 1.0
    }

    // Q fragments (B operand): col i = l16 of tile it, k = cc*32 + quad*8
    bf16x8 qf[2][2];
    #pragma unroll
    for (int it = 0; it < 2; ++it) {
        const int row = i0 + wave * 32 + it * 16 + l16;
        const short* qp = &q[((size_t)(b * NN + row)) * INNER + h * DH];
        qf[it][0] = *(const bf16x8*)&qp[quad * 8];
        qf[it][1] = *(const bf16x8*)&qp[32 + quad * 8];
    }

    f32x4 Oa[2][4];                      // [it][dt]: O rows quad*4+r, col dt*16+l16
    f32x4 La[2];                         // [it]: l rows quad*4+r (valid on l16==0)
    #pragma unroll
    for (int it = 0; it < 2; ++it) {
        La[it] = (f32x4){0.f, 0.f, 0.f, 0.f};
        #pragma unroll
        for (int dt = 0; dt < 4; ++dt) Oa[it][dt] = (f32x4){0.f, 0.f, 0.f, 0.f};
    }

    const int kjj = t >> 3, kdq = (t & 7) * 8;     // K staging
    const int vjp = t & 31, vd0 = (t >> 5) * 8;    // V staging (j-pairs)

    for (int j0 = 0; j0 < MM; j0 += JT) {
        __syncthreads();
        {   // stage K natural [j][d]
            #pragma unroll
            for (int ii = 0; ii < 2; ++ii) {
                const int jj = ii * 32 + kjj;
                *(bf16x8*)&Ks[jj][kdq] =
                    *(const bf16x8*)&kv[((size_t)(b * MM + j0 + jj)) * KVS + h * DH + kdq];
            }
        }
        {   // stage V transposed via j-pairs (short2 stores)
            const int jg = j0 + 2 * vjp;
            const short* vp0 = &kv[((size_t)(b * MM + jg))     * KVS + 512 + h * DH + vd0];
            const short* vp1 = &kv[((size_t)(b * MM + jg + 1)) * KVS + 512 + h * DH + vd0];
            bf16x8 va = *(const bf16x8*)vp0;
            bf16x8 vb = *(const bf16x8*)vp1;
            #pragma unroll
            for (int i = 0; i < 8; ++i) {
                short2 pr; pr.x = va[i]; pr.y = vb[i];
                *(short2*)&Vt[vd0 + i][2 * vjp] = pr;
            }
        }
        __syncthreads();

        // --- S^T = K Q^T per i-tile; p = exp2(s); truncation-pack to bf16
        #pragma unroll
        for (int it = 0; it < 2; ++it) {
            #pragma unroll
            for (int jt = 0; jt < 4; ++jt) {
                f32x4 c = (f32x4){0.f, 0.f, 0.f, 0.f};
                #pragma unroll
                for (int cc = 0; cc < 2; ++cc) {
                    bf16x8 kb = *(bf16x8*)&Ks[jt * 16 + l16][cc * 32 + quad * 8];
                    c = __builtin_amdgcn_mfma_f32_16x16x32_bf16(kb, qf[it][cc], c, 0, 0, 0);
                }
                const float e0 = exp2f(c[0]), e1 = exp2f(c[1]);
                const float e2 = exp2f(c[2]), e3 = exp2f(c[3]);
                uint2 pk;   // [bf16(e0)|bf16(e1)] , [bf16(e2)|bf16(e3)] (truncated)
                pk.x = __builtin_amdgcn_perm(__builtin_bit_cast(unsigned, e1),
                                             __builtin_bit_cast(unsigned, e0), 0x07060302u);
                pk.y = __builtin_amdgcn_perm(__builtin_bit_cast(unsigned, e3),
                                             __builtin_bit_cast(unsigned, e2), 0x07060302u);
                *(uint2*)&Ps[wave][it * 16 + l16][jt * 16 + quad * 4] = pk;
            }
        }

        // read P as A-operand fragments (within-wave LDS dependency)
        bf16x8 pa[2][2];
        #pragma unroll
        for (int it = 0; it < 2; ++it)
            #pragma unroll
            for (int cc = 0; cc < 2; ++cc)
                pa[it][cc] = *(bf16x8*)&Ps[wave][it * 16 + l16][cc * 32 + quad * 8];

        // --- O += P V : each V-frag read feeds both i-tiles
        #pragma unroll
        for (int dt = 0; dt < 4; ++dt) {
            #pragma unroll
            for (int cc = 0; cc < 2; ++cc) {
                bf16x8 vb = *(bf16x8*)&Vt[dt * 16 + l16][cc * 32 + quad * 8];
                #pragma unroll
                for (int it = 0; it < 2; ++it)
                    Oa[it][dt] = __builtin_amdgcn_mfma_f32_16x16x32_bf16(
                        pa[it][cc], vb, Oa[it][dt], 0, 0, 0);
            }
        }
        // --- l += P . 1 via ones-row
        #pragma unroll
        for (int cc = 0; cc < 2; ++cc) {
            bf16x8 vb1 = *(bf16x8*)&Vt[64 + l16][cc * 32 + quad * 8];
            #pragma unroll
            for (int it = 0; it < 2; ++it)
                La[it] = __builtin_amdgcn_mfma_f32_16x16x32_bf16(
                    pa[it][cc], vb1, La[it], 0, 0, 0);
        }
    }

    // epilogue: l[row=quad*4+r] lives in La[it][r] of lane quad*16
    #pragma unroll
    for (int it = 0; it < 2; ++it) {
        #pragma unroll
        for (int r = 0; r < 4; ++r) {
            const float lr = __shfl(La[it][r], quad * 16, 64);
            const float inv = 1.f / lr;
            const int row = i0 + wave * 32 + it * 16 + quad * 4 + r;
            #pragma unroll
            for (int dt = 0; dt < 4; ++dt)
                o[((size_t)(b * NN + row)) * INNER + h * DH + dt * 16 + l16] =
                    fbf(Oa[it][dt][r] * inv);
        }
    }
}

// ---------------------------------------------------------------------------
// Launch
// ---------------------------------------------------------------------------
extern "C" void kernel_launch(void* const* d_in, const int* in_sizes, int n_in,
                              void* d_out, int out_size, void* d_ws, size_t ws_size,
                              hipStream_t stream)
{
    const float* x     = (const float*)d_in[0];
    const float* cond  = (const float*)d_in[1];
    const float* lnx_g = (const float*)d_in[2];
    const float* lnx_b = (const float*)d_in[3];
    const float* lnc_g = (const float*)d_in[4];
    const float* lnc_b = (const float*)d_in[5];
    const float* Wq    = (const float*)d_in[6];
    const float* Wk    = (const float*)d_in[7];
    const float* Wv    = (const float*)d_in[8];
    const float* Wo    = (const float*)d_in[9];
    const float* bo    = (const float*)d_in[10];
    const float* lnf_g = (const float*)d_in[11];
    const float* lnf_b = (const float*)d_in[12];
    float* out = (float*)d_out;
    char* ws = (char*)d_ws;

    const int R = BB * NN;  // 8192

    // workspace layout (bytes, 16B-aligned)
    short* xn_bf  = (short*)(ws);                    //  8 MB
    short* cn_bf  = (short*)(ws + (8u << 20));       // 12 MB
    short* Wq_t   = (short*)(ws + (20u << 20));      // 0.5 MB
    short* Wo_t   = (short*)(ws + (21u << 20));      // 0.5 MB
    short* Wkv_t  = (short*)(ws + (22u << 20));      // 1.5 MB
    short* qb     = (short*)(ws + (24u << 20));      //  8 MB
    short* kvb    = (short*)(ws + (32u << 20));      // 16 MB
    short* ab     = (short*)(ws + (48u << 20));      //  8 MB
    short* ob     = (short*)(ws + (56u << 20));      //  8 MB (o-proj, bf16, no resid)

    transpose_cvt<<<dim3(16, DQ / 32),  256, 0, stream>>>(Wq, Wq_t, DQ);
    transpose_cvt<<<dim3(16, DC / 32),  256, 0, stream>>>(Wk, Wkv_t, DC);
    transpose_cvt<<<dim3(16, DC / 32),  256, 0, stream>>>(Wv, Wkv_t + (size_t)512 * DC, DC);
    transpose_cvt<<<dim3(16, INNER / 32), 256, 0, stream>>>(Wo, Wo_t, INNER);

    layernorm_bf16<<<R, 256, 0, stream>>>(x,    lnx_g, lnx_b, xn_bf, DQ);
    layernorm_bf16<<<R, 256, 0, stream>>>(cond, lnc_g, lnc_b, cn_bf, DC);

    // q = (xn @ Wq) * 0.125*log2(e)  (softmax becomes exp2; bf16 out)
    gemm_mfma<2><<<dim3(INNER / 64, R / GBM), 256, 0, stream>>>(
        xn_bf, Wq_t, DQ, INNER, 0.125f * 1.44269504089f, qb, nullptr, nullptr, nullptr);
    // [k|v] = cn @ [Wk|Wv] (bf16 out, Nout=1024)
    gemm_mfma<4><<<dim3(KVS / 128, R / GBM), 256, 0, stream>>>(
        cn_bf, Wkv_t, DC, KVS, 1.0f, kvb, nullptr, nullptr, nullptr);

    attention_mfma<<<dim3(NN / QT, NH, BB), 256, 0, stream>>>(qb, kvb, ab);

    // o-proj: bf16 out + bias (residual folded into the final LN)
    gemm_mfma<2><<<dim3(INNER / 64, R / GBM), 256, 0, stream>>>(
        ab, Wo_t, INNER, INNER, 1.0f, ob, nullptr, bo, nullptr);

    layernorm_res_f32<<<R, 256, 0, stream>>>(ob, x, lnf_g, lnf_b, out);
}

// Round 6
// 239.610 us; speedup vs baseline: 1.2385x; 1.2385x over previous
//
#include <hip/hip_runtime.h>
#include <hip/hip_bf16.h>
#include <math.h>

// Problem constants (CrossAttention_14955076125227)
//   B=4, N=2048, M=2048, Dq=512, Dc=768, H=8, Dh=64, inner=512
#define BB 4
#define NN 2048
#define MM 2048
#define DQ 512
#define DC 768
#define NH 8
#define DH 64
#define INNER 512
#define KVS 1024   // fused K|V row stride (bf16 elems)

typedef short bf16x8 __attribute__((ext_vector_type(8)));
typedef float f32x4  __attribute__((ext_vector_type(4)));

__device__ inline short fbf(float f) {
    __hip_bfloat16 h = __float2bfloat16(f);
    return __builtin_bit_cast(short, h);
}

// async global->LDS, 16 B per lane. LDS dest is wave-uniform base; HW adds lane*16.
__device__ inline void gld16(const void* gptr, void* lds_uniform_base) {
    __builtin_amdgcn_global_load_lds(
        (const __attribute__((address_space(1))) void*)gptr,
        (__attribute__((address_space(3))) void*)lds_uniform_base, 16, 0, 0);
}

// ---------------------------------------------------------------------------
// Fused LayerNorm pair -> bf16. grid (R, 2): y=0 -> x (D=512), y=1 -> cond (768)
// ---------------------------------------------------------------------------
__global__ __launch_bounds__(256) void ln2_bf16(
    const float* __restrict__ x, const float* __restrict__ cond,
    const float* __restrict__ gx, const float* __restrict__ bx,
    const float* __restrict__ gc, const float* __restrict__ bc,
    short* __restrict__ xn, short* __restrict__ cn)
{
    const int which = blockIdx.y;
    const float* in = which ? cond : x;
    const float* g  = which ? gc : gx;
    const float* bb = which ? bc : bx;
    short* out      = which ? cn : xn;
    const int D     = which ? DC : DQ;

    const int row = blockIdx.x;
    const float* xr = in + (size_t)row * D;
    float s = 0.f, s2 = 0.f;
    for (int d = threadIdx.x; d < D; d += 256) {
        float v = xr[d];
        s += v; s2 += v * v;
    }
    __shared__ float red[2][4];
    #pragma unroll
    for (int off = 32; off; off >>= 1) {
        s  += __shfl_down(s,  off, 64);
        s2 += __shfl_down(s2, off, 64);
    }
    const int wave = threadIdx.x >> 6, lane = threadIdx.x & 63;
    if (lane == 0) { red[0][wave] = s; red[1][wave] = s2; }
    __syncthreads();
    if (threadIdx.x == 0) {
        float ts = red[0][0] + red[0][1] + red[0][2] + red[0][3];
        float t2 = red[1][0] + red[1][1] + red[1][2] + red[1][3];
        float mu = ts / (float)D;
        float var = t2 / (float)D - mu * mu;
        red[0][0] = mu;
        red[1][0] = rsqrtf(var + 1e-5f);
    }
    __syncthreads();
    const float mu = red[0][0], rstd = red[1][0];
    short* o = out + (size_t)row * D;
    for (int d = threadIdx.x; d < D; d += 256)
        o[d] = fbf((xr[d] - mu) * rstd * g[d] + bb[d]);
}

// ---------------------------------------------------------------------------
// Final LayerNorm with fused residual: out = LN(bf16(ob) + x), D=512.
// ---------------------------------------------------------------------------
__global__ __launch_bounds__(256) void layernorm_res_f32(
    const short* __restrict__ ob, const float* __restrict__ x,
    const float* __restrict__ g, const float* __restrict__ b,
    float* __restrict__ out)
{
    const int row = blockIdx.x;
    const int t = threadIdx.x;
    const size_t base = (size_t)row * DQ;
    float v0, v1;
    {
        unsigned u0 = (unsigned)(unsigned short)ob[base + t];
        unsigned u1 = (unsigned)(unsigned short)ob[base + t + 256];
        v0 = __builtin_bit_cast(float, u0 << 16) + x[base + t];
        v1 = __builtin_bit_cast(float, u1 << 16) + x[base + t + 256];
    }
    float s = v0 + v1, s2 = v0 * v0 + v1 * v1;
    __shared__ float red[2][4];
    #pragma unroll
    for (int off = 32; off; off >>= 1) {
        s  += __shfl_down(s,  off, 64);
        s2 += __shfl_down(s2, off, 64);
    }
    const int wave = t >> 6, lane = t & 63;
    if (lane == 0) { red[0][wave] = s; red[1][wave] = s2; }
    __syncthreads();
    if (t == 0) {
        float ts = red[0][0] + red[0][1] + red[0][2] + red[0][3];
        float t2 = red[1][0] + red[1][1] + red[1][2] + red[1][3];
        float mu = ts / (float)DQ;
        float var = t2 / (float)DQ - mu * mu;
        red[0][0] = mu;
        red[1][0] = rsqrtf(var + 1e-5f);
    }
    __syncthreads();
    const float mu = red[0][0], rstd = red[1][0];
    out[base + t]       = (v0 - mu) * rstd * g[t]       + b[t];
    out[base + t + 256] = (v1 - mu) * rstd * g[t + 256] + b[t + 256];
}

// ---------------------------------------------------------------------------
// Fused transpose+cvt of all 4 weights. grid (16, 80):
//  y<16: Wq(K=512) -> Wqt; y<40: Wk(768) -> Wkvt rows 0..511;
//  y<64: Wv(768) -> Wkvt rows 512..1023; else Wo(512) -> Wot.
// ---------------------------------------------------------------------------
__global__ __launch_bounds__(256) void transpose4(
    const float* __restrict__ Wq, const float* __restrict__ Wk,
    const float* __restrict__ Wv, const float* __restrict__ Wo,
    short* __restrict__ Wqt, short* __restrict__ Wkvt, short* __restrict__ Wot)
{
    const int y = blockIdx.y;
    const float* W; short* Wt; int K, k0;
    if (y < 16)      { W = Wq; Wt = Wqt;  K = DQ; k0 = y * 32; }
    else if (y < 40) { W = Wk; Wt = Wkvt; K = DC; k0 = (y - 16) * 32; }
    else if (y < 64) { W = Wv; Wt = Wkvt + (size_t)512 * DC; K = DC; k0 = (y - 40) * 32; }
    else             { W = Wo; Wt = Wot;  K = DQ; k0 = (y - 64) * 32; }

    __shared__ float tile[32][33];
    const int t = threadIdx.x;
    const int n0 = blockIdx.x * 32;
    const int r = t >> 3, c4 = (t & 7) * 4;
    float4 vv = *(const float4*)&W[(size_t)(k0 + r) * 512 + n0 + c4];
    tile[c4 + 0][r] = vv.x; tile[c4 + 1][r] = vv.y;
    tile[c4 + 2][r] = vv.z; tile[c4 + 3][r] = vv.w;
    __syncthreads();
    short4 s;
    s.x = fbf(tile[r][c4 + 0]); s.y = fbf(tile[r][c4 + 1]);
    s.z = fbf(tile[r][c4 + 2]); s.w = fbf(tile[r][c4 + 3]);
    *(short4*)&Wt[(size_t)(n0 + r) * K + k0 + c4] = s;
}

// ---------------------------------------------------------------------------
// Fused q+kv projection GEMM. grid (12, 64):
//  x<4 : q = (xn @ Wq)*qsc, Nout=512, K=512
//  x>=4: kv = cn @ [Wk|Wv], Nout=1024, K=768
// 128x128 tile, BK=32, 256 thr (4 waves 2x2; wave 64x64 = 4x4 MFMAs).
// ---------------------------------------------------------------------------
#define GBK 32

__global__ __launch_bounds__(256) void qkv_gemm(
    const short* __restrict__ xn, const short* __restrict__ cn,
    const short* __restrict__ Wqt, const short* __restrict__ Wkvt,
    short* __restrict__ qb, short* __restrict__ kvb, float qsc)
{
    const short* A; const short* Bt; short* outp; int K, Nout, n0; float sc;
    if (blockIdx.x < 4) {
        A = xn; Bt = Wqt; outp = qb; K = DQ; Nout = 512;
        n0 = blockIdx.x * 128; sc = qsc;
    } else {
        A = cn; Bt = Wkvt; outp = kvb; K = DC; Nout = 1024;
        n0 = (blockIdx.x - 4) * 128; sc = 1.f;
    }
    __shared__ short As[128 * GBK];
    __shared__ short Bs[128 * GBK];
    const int t = threadIdx.x;
    const int w = t >> 6, lane = t & 63;
    const int quad = lane >> 4, l16 = lane & 15;
    const int m0 = blockIdx.y * 128;
    const int wm = (w >> 1) * 64, wn = (w & 1) * 64;

    f32x4 acc[4][4];
    #pragma unroll
    for (int i = 0; i < 4; ++i)
        #pragma unroll
        for (int j = 0; j < 4; ++j) acc[i][j] = (f32x4){0.f, 0.f, 0.f, 0.f};

    for (int kt = 0; kt < K; kt += GBK) {
        __syncthreads();
        #pragma unroll
        for (int i = 0; i < 2; ++i) {
            const int j = w * 2 + i;
            const int c = j * 64 + lane;
            gld16(&A[(size_t)(m0 + (c >> 2)) * K + kt + (c & 3) * 8],
                  (char*)As + j * 1024);
            gld16(&Bt[(size_t)(n0 + (c >> 2)) * K + kt + (c & 3) * 8],
                  (char*)Bs + j * 1024);
        }
        __syncthreads();

        bf16x8 af[4], bfr[4];
        #pragma unroll
        for (int mt = 0; mt < 4; ++mt)
            af[mt] = *(bf16x8*)&As[(wm + mt * 16 + l16) * GBK + quad * 8];
        #pragma unroll
        for (int nt = 0; nt < 4; ++nt)
            bfr[nt] = *(bf16x8*)&Bs[(wn + nt * 16 + l16) * GBK + quad * 8];
        #pragma unroll
        for (int mt = 0; mt < 4; ++mt)
            #pragma unroll
            for (int nt = 0; nt < 4; ++nt)
                acc[mt][nt] = __builtin_amdgcn_mfma_f32_16x16x32_bf16(
                    af[mt], bfr[nt], acc[mt][nt], 0, 0, 0);
    }

    #pragma unroll
    for (int mt = 0; mt < 4; ++mt)
        #pragma unroll
        for (int r = 0; r < 4; ++r) {
            const int m = m0 + wm + mt * 16 + quad * 4 + r;
            #pragma unroll
            for (int nt = 0; nt < 4; ++nt) {
                const int n = n0 + wn + nt * 16 + l16;
                outp[(size_t)m * Nout + n] = fbf(acc[mt][nt][r] * sc);
            }
        }
}

// ---------------------------------------------------------------------------
// o-proj GEMM (m97 pattern): C = ab @ Wot^T + bias, bf16 out.
// Tile 128x64, BK=32, 256 thr.
// ---------------------------------------------------------------------------
__global__ __launch_bounds__(256) void oproj_gemm(
    const short* __restrict__ A, const short* __restrict__ Bt,
    short* __restrict__ outb, const float* __restrict__ bias)
{
    const int K = INNER, Nout = INNER;
    __shared__ short As[128 * GBK];
    __shared__ short Bs[64 * GBK];
    const int t = threadIdx.x;
    const int w = t >> 6, lane = t & 63;
    const int quad = lane >> 4, l16 = lane & 15;
    const int m0 = blockIdx.y * 128, n0 = blockIdx.x * 64;
    const int wm = (w >> 1) * 64, wn = (w & 1) * 32;

    f32x4 acc[4][2];
    #pragma unroll
    for (int i = 0; i < 4; ++i)
        #pragma unroll
        for (int j = 0; j < 2; ++j) acc[i][j] = (f32x4){0.f, 0.f, 0.f, 0.f};

    for (int kt = 0; kt < K; kt += GBK) {
        __syncthreads();
        #pragma unroll
        for (int i = 0; i < 2; ++i) {
            const int j = w * 2 + i;
            const int c = j * 64 + lane;
            gld16(&A[(size_t)(m0 + (c >> 2)) * K + kt + (c & 3) * 8],
                  (char*)As + j * 1024);
        }
        {
            const int c = w * 64 + lane;
            gld16(&Bt[(size_t)(n0 + (c >> 2)) * K + kt + (c & 3) * 8],
                  (char*)Bs + w * 1024);
        }
        __syncthreads();

        bf16x8 af[4], bfr[2];
        #pragma unroll
        for (int mt = 0; mt < 4; ++mt)
            af[mt] = *(bf16x8*)&As[(wm + mt * 16 + l16) * GBK + quad * 8];
        #pragma unroll
        for (int nt = 0; nt < 2; ++nt)
            bfr[nt] = *(bf16x8*)&Bs[(wn + nt * 16 + l16) * GBK + quad * 8];
        #pragma unroll
        for (int mt = 0; mt < 4; ++mt)
            #pragma unroll
            for (int nt = 0; nt < 2; ++nt)
                acc[mt][nt] = __builtin_amdgcn_mfma_f32_16x16x32_bf16(
                    af[mt], bfr[nt], acc[mt][nt], 0, 0, 0);
    }

    #pragma unroll
    for (int mt = 0; mt < 4; ++mt)
        #pragma unroll
        for (int r = 0; r < 4; ++r) {
            const int m = m0 + wm + mt * 16 + quad * 4 + r;
            #pragma unroll
            for (int nt = 0; nt < 2; ++nt) {
                const int n = n0 + wn + nt * 16 + l16;
                outb[(size_t)m * Nout + n] = fbf(acc[mt][nt][r] + bias[n]);
            }
        }
}

// ---------------------------------------------------------------------------
// bf16-MFMA flash attention v4: S^T form, no-max softmax, 2 i-tiles/wave,
// intra-block j-split. Block = 512 thr = 8 waves; waves 0-3 do j in [0,1024),
// waves 4-7 do [1024,2048) over the SAME 128 Q rows. O,l are additive across
// j (no running max) -> one-time LDS combine at the end.
// Grid (N/128, H, B) = 512 blocks; LDS 78.8 KB -> 2 blocks/CU = 16 waves/CU.
// q is PRE-SCALED by 0.125*log2(e) in the q-proj GEMM (p = exp2(s)).
// ---------------------------------------------------------------------------
#define QT 128
#define JT 64
#define KSTR 72      // 144 B rows: 16B-aligned, max 2-way bank alias (free)
#define MH (MM / 2)  // 1024 j's per wave-group

__global__ __launch_bounds__(512) void attention_mfma(
    const short* __restrict__ q, const short* __restrict__ kv,
    short* __restrict__ o)
{
    const int b = blockIdx.z, h = blockIdx.y;
    const int i0 = blockIdx.x * QT;
    const int t = threadIdx.x;
    const int wave = t >> 6, lane = t & 63;
    const int w4 = wave & 3, hh = wave >> 2;   // row-group, j-half
    const int quad = lane >> 4, l16 = lane & 15;

    // manual LDS layout (Obuf overlays Ps for the final combine)
    __shared__ __align__(16) char smem[78848];
    short (*Ks)[64][KSTR] = (short(*)[64][KSTR])(smem);           // [2] 18432 B
    short (*Vt)[80][KSTR] = (short(*)[80][KSTR])(smem + 18432);   // [2] 23040 B
    short (*Ps)[32][KSTR] = (short(*)[32][KSTR])(smem + 41472);   // [8] 36864 B
    float (*Lbuf)[32]     = (float(*)[32])(smem + 78336);         // [4][32]
    float (*Obuf)[32][68] = (float(*)[32][68])(smem + 41472);     // overlays Ps

    // init ones/zero rows 64..79 of both Vt halves (bf16 1.0 row for l-sum)
    for (int idx = t; idx < 2 * 16 * KSTR; idx += 512) {
        const int half = idx / (16 * KSTR);
        const int rem  = idx % (16 * KSTR);
        const int rr   = rem / KSTR;
        Vt[half][64 + rr][rem % KSTR] = (rr == 0) ? (short)0x3F80 : (short)0;
    }

    // Q fragments (B operand): col i = l16 of tile it, k = cc*32 + quad*8
    bf16x8 qf[2][2];
    #pragma unroll
    for (int it = 0; it < 2; ++it) {
        const int row = i0 + w4 * 32 + it * 16 + l16;
        const short* qp = &q[((size_t)(b * NN + row)) * INNER + h * DH];
        qf[it][0] = *(const bf16x8*)&qp[quad * 8];
        qf[it][1] = *(const bf16x8*)&qp[32 + quad * 8];
    }

    f32x4 Oa[2][4];   // [it][dt]: rows quad*4+r, col dt*16+l16 (unnormalized)
    f32x4 La[2];      // [it]: l rows quad*4+r (valid on l16==0 lanes)
    #pragma unroll
    for (int it = 0; it < 2; ++it) {
        La[it] = (f32x4){0.f, 0.f, 0.f, 0.f};
        #pragma unroll
        for (int dt = 0; dt < 4; ++dt) Oa[it][dt] = (f32x4){0.f, 0.f, 0.f, 0.f};
    }

    // staging: threads 0-255 stage j-half 0, 256-511 stage half 1
    const int tt = t & 255, th = t >> 8;
    const int kjj = tt >> 3, kdq = (tt & 7) * 8;   // K: 32 rows x 8 chunks, x2
    const int vjp = tt & 31, vd0 = (tt >> 5) * 8;  // V: j-pair, 8 d each

    for (int jj0 = 0; jj0 < MH; jj0 += JT) {
        __syncthreads();
        {   // stage K natural [j][d] for half th
            const int j0 = th * MH + jj0;
            #pragma unroll
            for (int ii = 0; ii < 2; ++ii) {
                const int jj = ii * 32 + kjj;
                *(bf16x8*)&Ks[th][jj][kdq] =
                    *(const bf16x8*)&kv[((size_t)(b * MM + j0 + jj)) * KVS + h * DH + kdq];
            }
            // stage V transposed via j-pairs (short2 stores)
            const int jg = j0 + 2 * vjp;
            const short* vp0 = &kv[((size_t)(b * MM + jg))     * KVS + 512 + h * DH + vd0];
            const short* vp1 = &kv[((size_t)(b * MM + jg + 1)) * KVS + 512 + h * DH + vd0];
            bf16x8 va = *(const bf16x8*)vp0;
            bf16x8 vb = *(const bf16x8*)vp1;
            #pragma unroll
            for (int i = 0; i < 8; ++i) {
                short2 pr; pr.x = va[i]; pr.y = vb[i];
                *(short2*)&Vt[th][vd0 + i][2 * vjp] = pr;
            }
        }
        __syncthreads();

        // --- S^T = K Q^T per i-tile; p = exp2(s); truncation-pack to bf16
        #pragma unroll
        for (int it = 0; it < 2; ++it) {
            #pragma unroll
            for (int jt = 0; jt < 4; ++jt) {
                f32x4 c = (f32x4){0.f, 0.f, 0.f, 0.f};
                #pragma unroll
                for (int cc = 0; cc < 2; ++cc) {
                    bf16x8 kb = *(bf16x8*)&Ks[hh][jt * 16 + l16][cc * 32 + quad * 8];
                    c = __builtin_amdgcn_mfma_f32_16x16x32_bf16(kb, qf[it][cc], c, 0, 0, 0);
                }
                const float e0 = exp2f(c[0]), e1 = exp2f(c[1]);
                const float e2 = exp2f(c[2]), e3 = exp2f(c[3]);
                uint2 pk;
                pk.x = __builtin_amdgcn_perm(__builtin_bit_cast(unsigned, e1),
                                             __builtin_bit_cast(unsigned, e0), 0x07060302u);
                pk.y = __builtin_amdgcn_perm(__builtin_bit_cast(unsigned, e3),
                                             __builtin_bit_cast(unsigned, e2), 0x07060302u);
                *(uint2*)&Ps[wave][it * 16 + l16][jt * 16 + quad * 4] = pk;
            }
        }

        // read P as A-operand fragments (within-wave LDS dependency)
        bf16x8 pa[2][2];
        #pragma unroll
        for (int it = 0; it < 2; ++it)
            #pragma unroll
            for (int cc = 0; cc < 2; ++cc)
                pa[it][cc] = *(bf16x8*)&Ps[wave][it * 16 + l16][cc * 32 + quad * 8];

        // --- O += P V (each V-frag feeds both i-tiles); l += P . ones
        #pragma unroll
        for (int dt = 0; dt < 4; ++dt) {
            #pragma unroll
            for (int cc = 0; cc < 2; ++cc) {
                bf16x8 vb = *(bf16x8*)&Vt[hh][dt * 16 + l16][cc * 32 + quad * 8];
                #pragma unroll
                for (int it = 0; it < 2; ++it)
                    Oa[it][dt] = __builtin_amdgcn_mfma_f32_16x16x32_bf16(
                        pa[it][cc], vb, Oa[it][dt], 0, 0, 0);
            }
        }
        #pragma unroll
        for (int cc = 0; cc < 2; ++cc) {
            bf16x8 vb1 = *(bf16x8*)&Vt[hh][64 + l16][cc * 32 + quad * 8];
            #pragma unroll
            for (int it = 0; it < 2; ++it)
                La[it] = __builtin_amdgcn_mfma_f32_16x16x32_bf16(
                    pa[it][cc], vb1, La[it], 0, 0, 0);
        }
    }

    // ---- combine the two j-halves (O, l additive) via LDS ----
    __syncthreads();   // all Ps reads done; safe to overlay Obuf
    if (wave >= 4) {
        #pragma unroll
        for (int it = 0; it < 2; ++it) {
            #pragma unroll
            for (int r = 0; r < 4; ++r) {
                const int qr = it * 16 + quad * 4 + r;
                #pragma unroll
                for (int dt = 0; dt < 4; ++dt)
                    Obuf[w4][qr][dt * 16 + l16] = Oa[it][dt][r];
                if (l16 == 0) Lbuf[w4][qr] = La[it][r];
            }
        }
    }
    __syncthreads();
    if (wave < 4) {
        #pragma unroll
        for (int it = 0; it < 2; ++it) {
            #pragma unroll
            for (int r = 0; r < 4; ++r) {
                const int qr = it * 16 + quad * 4 + r;
                const float ltot = __shfl(La[it][r], quad * 16, 64) + Lbuf[w4][qr];
                const float inv = 1.f / ltot;
                const int row = i0 + w4 * 32 + qr;
                #pragma unroll
                for (int dt = 0; dt < 4; ++dt) {
                    const float val = Oa[it][dt][r] + Obuf[w4][qr][dt * 16 + l16];
                    o[((size_t)(b * NN + row)) * INNER + h * DH + dt * 16 + l16] =
                        fbf(val * inv);
                }
            }
        }
    }
}

// ---------------------------------------------------------------------------
// Launch
// ---------------------------------------------------------------------------
extern "C" void kernel_launch(void* const* d_in, const int* in_sizes, int n_in,
                              void* d_out, int out_size, void* d_ws, size_t ws_size,
                              hipStream_t stream)
{
    const float* x     = (const float*)d_in[0];
    const float* cond  = (const float*)d_in[1];
    const float* lnx_g = (const float*)d_in[2];
    const float* lnx_b = (const float*)d_in[3];
    const float* lnc_g = (const float*)d_in[4];
    const float* lnc_b = (const float*)d_in[5];
    const float* Wq    = (const float*)d_in[6];
    const float* Wk    = (const float*)d_in[7];
    const float* Wv    = (const float*)d_in[8];
    const float* Wo    = (const float*)d_in[9];
    const float* bo    = (const float*)d_in[10];
    const float* lnf_g = (const float*)d_in[11];
    const float* lnf_b = (const float*)d_in[12];
    float* out = (float*)d_out;
    char* ws = (char*)d_ws;

    const int R = BB * NN;  // 8192

    // workspace layout (bytes, 16B-aligned)
    short* xn_bf  = (short*)(ws);                    //  8 MB
    short* cn_bf  = (short*)(ws + (8u << 20));       // 12 MB
    short* Wq_t   = (short*)(ws + (20u << 20));      // 0.5 MB
    short* Wo_t   = (short*)(ws + (21u << 20));      // 0.5 MB
    short* Wkv_t  = (short*)(ws + (22u << 20));      // 1.5 MB
    short* qb     = (short*)(ws + (24u << 20));      //  8 MB
    short* kvb    = (short*)(ws + (32u << 20));      // 16 MB
    short* ab     = (short*)(ws + (48u << 20));      //  8 MB
    short* ob     = (short*)(ws + (56u << 20));      //  8 MB

    transpose4<<<dim3(16, 80), 256, 0, stream>>>(Wq, Wk, Wv, Wo, Wq_t, Wkv_t, Wo_t);

    ln2_bf16<<<dim3(R, 2), 256, 0, stream>>>(
        x, cond, lnx_g, lnx_b, lnc_g, lnc_b, xn_bf, cn_bf);

    // q = (xn @ Wq)*0.125*log2e ; [k|v] = cn @ [Wk|Wv]  (one launch, 768 blocks)
    qkv_gemm<<<dim3(12, R / 128), 256, 0, stream>>>(
        xn_bf, cn_bf, Wq_t, Wkv_t, qb, kvb, 0.125f * 1.44269504089f);

    attention_mfma<<<dim3(NN / QT, NH, BB), 512, 0, stream>>>(qb, kvb, ab);

    // o-proj: bf16 out + bias (residual folded into the final LN)
    oproj_gemm<<<dim3(INNER / 64, R / 128), 256, 0, stream>>>(ab, Wo_t, ob, bo);

    layernorm_res_f32<<<R, 256, 0, stream>>>(ob, x, lnf_g, lnf_b, out);
}